// Round 2
// baseline (2603.154 us; speedup 1.0000x reference)
//
#include <hip/hip_runtime.h>
#include <hip/hip_bf16.h>

// GenericLSTM: B=64 T=2048 I=128 H=256, fp32 in/out.
// R2 design: gx = inputs@W_x via bf16 MFMA GEMM (f16 out, gate-interleaved
// cols col'=j*4+g). Recurrent kernel: 64 WGs x 256 threads; thread j owns all
// 4 gates of H-col j (epilogue fully thread-local, 1 barrier/step). W_h int8
// resident in 256 VGPRs; h int8 in LDS (64 dwords, double-buffered); per step
// each WAVE does ONE ds_read_b32 then v_readlane broadcasts -> sdot4.

#define B_ 64
#define T_ 2048
#define I_ 128
#define H_ 256
#define NC 1024  // 4 gates * H columns

typedef __attribute__((ext_vector_type(8))) short bf16x8;
typedef __attribute__((ext_vector_type(4))) float f32x4;
typedef __attribute__((ext_vector_type(4))) _Float16 f16x4;

static __device__ __forceinline__ unsigned short f2bf(float f) {
    unsigned u = __builtin_bit_cast(unsigned, f);
    u = (u + 0x7FFFu + ((u >> 16) & 1u)) >> 16;
    return (unsigned short)u;
}

static __device__ __forceinline__ int dot4(unsigned a, unsigned b, int c) {
#if __has_builtin(__builtin_amdgcn_sdot4)
    return __builtin_amdgcn_sdot4((int)a, (int)b, c, false);
#else
    int r = c;
    r += (int)(signed char)(a) * (int)(signed char)(b);
    r += (int)(signed char)(a >> 8) * (int)(signed char)(b >> 8);
    r += (int)(signed char)(a >> 16) * (int)(signed char)(b >> 16);
    r += (int)(signed char)(a >> 24) * (int)(signed char)(b >> 24);
    return r;
#endif
}

// ---------------- P1: W_h [4,256,256] f32 -> int8, per-col scale, col
// interleaved: colp = j*4 + g. wq[colp*64 + lane] packs k=4*lane..4*lane+3.
__global__ void pack_wh(const float* __restrict__ Wh, unsigned* __restrict__ wq,
                        float* __restrict__ sws) {
    int colp = blockIdx.x;             // j*4+g
    int g = colp & 3, j = colp >> 2;
    int lane = threadIdx.x;            // k = 4*lane..4*lane+3
    float v[4];
    float m = 0.f;
#pragma unroll
    for (int u = 0; u < 4; ++u) {
        int k = lane * 4 + u;
        v[u] = Wh[(g * H_ + k) * H_ + j];
        m = fmaxf(m, fabsf(v[u]));
    }
#pragma unroll
    for (int off = 32; off; off >>= 1) m = fmaxf(m, __shfl_xor(m, off));
    float mm = (m > 0.f) ? m : 1.f;
    float inv = 127.f / mm;
    unsigned pack = 0;
#pragma unroll
    for (int u = 0; u < 4; ++u) {
        int q = (int)rintf(v[u] * inv);
        q = max(-127, min(127, q));
        pack |= ((unsigned)(q & 255)) << (8 * u);
    }
    wq[colp * 64 + lane] = pack;
    if (lane == 0) sws[colp] = mm / (127.f * 127.f);  // folds h 1/127 dequant
}

// ---------------- P2: W_x [4,128,256] f32 -> bf16 MFMA B-fragments, output
// col colp = h*4 + g: Bfrag[(c16*1024 + colp)*8 + jj] = W_x[g][k][h].
__global__ void pack_wx(const float* __restrict__ Wx,
                        unsigned short* __restrict__ bxp) {
    int f = blockIdx.x * blockDim.x + threadIdx.x;  // 0..131071
    int jj = f & 7;
    int colp = (f >> 3) & 1023;
    int c16 = f >> 13;  // 0..15
    int k = (c16 >> 2) * 32 + (c16 & 3) * 8 + jj;
    int g = colp & 3, h = colp >> 2;
    bxp[f] = f2bf(Wx[(g * I_ + k) * H_ + h]);
}

// ---------------- GEMM: gx[row][colp] = sum_k inputs[row][k]*Wx[k][colp]
// rows=131072, cols=1024, K=128 single shot. f16 output.
__global__ __launch_bounds__(256) void gemm_gx(
    const float* __restrict__ A, const unsigned short* __restrict__ Bp,
    unsigned short* __restrict__ Cg) {
    __shared__ uint4 sm[4096];  // 64 KB: As=[0..2047], Bs=[2048..4095]
    int tid = threadIdx.x;
    int mt = blockIdx.x, nt = blockIdx.y;

    const float* Ab = A + (size_t)mt * 128 * I_;
    unsigned* dstA = (unsigned*)sm;
#pragma unroll
    for (int it = 0; it < 16; ++it) {
        int flat = it * 1024 + tid * 4;
        float4 a4 = *(const float4*)(Ab + flat);
        int m = flat >> 7, k0 = flat & 127;
        int c16 = k0 >> 3, j0 = k0 & 7;  // j0 in {0,4}
        unsigned lo = (unsigned)f2bf(a4.x) | ((unsigned)f2bf(a4.y) << 16);
        unsigned hi = (unsigned)f2bf(a4.z) | ((unsigned)f2bf(a4.w) << 16);
        int didx = ((c16 * 128 + m) * 16 + j0 * 2) >> 2;
        dstA[didx] = lo;
        dstA[didx + 1] = hi;
    }
    const uint4* Bq = (const uint4*)Bp;
#pragma unroll
    for (int it = 0; it < 8; ++it) {
        int chunk = it * 2 + (tid >> 7);
        int inner = tid & 127;
        sm[2048 + chunk * 128 + inner] = Bq[chunk * 1024 + nt * 128 + inner];
    }
    __syncthreads();

    int wid = tid >> 6, lane = tid & 63;
    int r = lane & 15, q = lane >> 4;
    int mw = (wid & 1) * 64, nw = (wid >> 1) * 64;
    f32x4 acc[4][4] = {};
#pragma unroll
    for (int ki = 0; ki < 4; ++ki) {
        bf16x8 af[4], bfr[4];
#pragma unroll
        for (int x = 0; x < 4; ++x) {
            af[x] = __builtin_bit_cast(bf16x8,
                                       sm[(ki * 4 + q) * 128 + mw + x * 16 + r]);
            bfr[x] = __builtin_bit_cast(
                bf16x8, sm[2048 + (ki * 4 + q) * 128 + nw + x * 16 + r]);
        }
#pragma unroll
        for (int x = 0; x < 4; ++x)
#pragma unroll
            for (int y = 0; y < 4; ++y)
                acc[x][y] = __builtin_amdgcn_mfma_f32_16x16x32_bf16(
                    af[x], bfr[y], acc[x][y], 0, 0, 0);
    }
    __syncthreads();

    _Float16* ct = (_Float16*)sm;
#pragma unroll
    for (int x = 0; x < 4; ++x)
#pragma unroll
        for (int y = 0; y < 4; ++y)
#pragma unroll
            for (int g2 = 0; g2 < 4; ++g2) {
                int row = mw + x * 16 + q * 4 + g2;
                int colc = nw + y * 16 + r;
                ct[row * 128 + colc] = (_Float16)acc[x][y][g2];
            }
    __syncthreads();
    int m = tid >> 1, half = tid & 1;
    const uint4* src = (const uint4*)sm;
    uint4* dstg =
        (uint4*)(Cg + ((size_t)(mt * 128 + m) * NC + nt * 128 + half * 64));
#pragma unroll
    for (int i = 0; i < 8; ++i) dstg[i] = src[m * 16 + half * 8 + i];
}

// ---------------- Recurrent kernel: 64 WGs x 256 threads, thread j owns
// H-col j (all 4 gates). Weights in 256 VGPRs. h int8 in LDS (64 dwords,
// double buffered); per wave: 1 ds_read_b32 + readlane broadcast.
__global__ __launch_bounds__(256, 1) void lstm_rec(
    const unsigned short* __restrict__ gx, const uint4* __restrict__ wq4,
    const float* __restrict__ sws, const float* __restrict__ bias,
    float* __restrict__ out) {
    int b = blockIdx.x, j = threadIdx.x;
    int lane = j & 63;

    unsigned w0[64], w1[64], w2[64], w3[64];
#pragma unroll
    for (int ii = 0; ii < 16; ++ii) {
        uint4 v0 = wq4[(j * 4 + 0) * 16 + ii];
        uint4 v1 = wq4[(j * 4 + 1) * 16 + ii];
        uint4 v2 = wq4[(j * 4 + 2) * 16 + ii];
        uint4 v3 = wq4[(j * 4 + 3) * 16 + ii];
        w0[4 * ii] = v0.x; w0[4 * ii + 1] = v0.y; w0[4 * ii + 2] = v0.z; w0[4 * ii + 3] = v0.w;
        w1[4 * ii] = v1.x; w1[4 * ii + 1] = v1.y; w1[4 * ii + 2] = v1.z; w1[4 * ii + 3] = v1.w;
        w2[4 * ii] = v2.x; w2[4 * ii + 1] = v2.y; w2[4 * ii + 2] = v2.z; w2[4 * ii + 3] = v2.w;
        w3[4 * ii] = v3.x; w3[4 * ii + 1] = v3.y; w3[4 * ii + 2] = v3.z; w3[4 * ii + 3] = v3.w;
    }
    float s0 = sws[j * 4 + 0], s1 = sws[j * 4 + 1];
    float s2 = sws[j * 4 + 2], s3 = sws[j * 4 + 3];
    float bb0 = bias[0 * H_ + j], bb1 = bias[1 * H_ + j];
    float bb2 = bias[2 * H_ + j], bb3 = bias[3 * H_ + j];

    __shared__ unsigned hbuf[2][64];
    if (j < 64) hbuf[0][j] = 0u;
    __syncthreads();

    float c = 0.f;
    const _Float16* gxh = (const _Float16*)gx;
    size_t rowbase = (size_t)b * T_;
    f16x4 gv = *(const f16x4*)(gxh + rowbase * NC + j * 4);

    for (int t = 0; t < T_; ++t) {
        size_t row = rowbase + t;
        // prefetch next step (t=2047 reads past gx region but inside ws)
        f16x4 nv = *(const f16x4*)(gxh + (row + 1) * NC + j * 4);

        unsigned hd = hbuf[t & 1][lane];  // wave holds all 64 h-dwords
        int a0 = 0, a1 = 0, a2 = 0, a3 = 0;
#pragma unroll
        for (int i = 0; i < 64; ++i) {
            unsigned hs = (unsigned)__builtin_amdgcn_readlane((int)hd, i);
            a0 = dot4(hs, w0[i], a0);
            a1 = dot4(hs, w1[i], a1);
            a2 = dot4(hs, w2[i], a2);
            a3 = dot4(hs, w3[i], a3);
        }
        float g0 = (float)a0 * s0 + (float)gv.x + bb0;  // input gate
        float g1 = (float)a1 * s1 + (float)gv.y + bb1;  // forget gate
        float g2 = (float)a2 * s2 + (float)gv.z + bb2;  // context (tanh)
        float g3 = (float)a3 * s3 + (float)gv.w + bb3;  // output gate

        float ig = 1.f / (1.f + __expf(-g0));
        float fg = 1.f / (1.f + __expf(-g1));
        float gg = 2.f / (1.f + __expf(-2.f * g2)) - 1.f;  // tanh, inf-safe
        float og = 1.f / (1.f + __expf(-g3));
        c = fg * c + ig * gg;
        float th = 2.f / (1.f + __expf(-2.f * c)) - 1.f;
        float h = og * th;
        out[row * H_ + j] = h;
        int qv = (int)rintf(h * 127.f);  // |h|<1 -> no clamp needed
        ((signed char*)hbuf[(t + 1) & 1])[j] = (signed char)qv;
        __syncthreads();  // h(t+1) complete before any wave reads it
        gv = nv;
    }
}

extern "C" void kernel_launch(void* const* d_in, const int* in_sizes, int n_in,
                              void* d_out, int out_size, void* d_ws,
                              size_t ws_size, hipStream_t stream) {
    const float* inputs = (const float*)d_in[0];
    const float* Wx = (const float*)d_in[1];
    const float* Wh = (const float*)d_in[2];
    const float* bias = (const float*)d_in[3];
    float* out = (float*)d_out;

    char* ws = (char*)d_ws;
    unsigned short* gxbuf = (unsigned short*)ws;   // 256 MiB f16 gx
    size_t off = (size_t)B_ * T_ * NC * 2;
    unsigned* wq = (unsigned*)(ws + off);          // 256 KiB int8 W_h
    off += (size_t)NC * 64 * 4;
    float* sws = (float*)(ws + off);               // 4 KiB scales
    off += (size_t)NC * 4;
    unsigned short* bxp = (unsigned short*)(ws + off);  // 256 KiB bf16 W_x
    off += (size_t)I_ * NC * 2;

    pack_wh<<<NC, 64, 0, stream>>>(Wh, wq, sws);
    pack_wx<<<(I_ * NC) / 256, 256, 0, stream>>>(Wx, bxp);
    gemm_gx<<<dim3((B_ * T_) / 128, NC / 128), 256, 0, stream>>>(inputs, bxp,
                                                                 gxbuf);
    lstm_rec<<<B_, 256, 0, stream>>>(gxbuf, (const uint4*)wq, sws, bias, out);
}